// Round 7
// baseline (399.918 us; speedup 1.0000x reference)
//
#include <hip/hip_runtime.h>
#include <hip/hip_bf16.h>
#include <math.h>

#define T_SEQ 2048
#define NHEAD 16
#define DQK 192      // NOPE + ROPE
#define DNOPE 128
#define DROPE 64
#define LORA_D 512
#define VDIM 128
#define SCALE_F 0.072168783648703216f  // 1/sqrt(192)
#define KC 32

typedef short bf16x8 __attribute__((ext_vector_type(8)));   // 8 bf16 = 4 VGPRs
typedef float f32x4 __attribute__((ext_vector_type(4)));

static __device__ __forceinline__ unsigned short f2bf(float x) {
  union { float f; unsigned int u; } v; v.f = x;
  unsigned int r = (v.u + 0x7fff + ((v.u >> 16) & 1)) >> 16;  // RNE
  return (unsigned short)r;
}
static __device__ __forceinline__ unsigned int pkbf(float a, float b) {
  return (unsigned int)f2bf(a) | ((unsigned int)f2bf(b) << 16);
}

// ---------------------------------------------------------------------------
// stage_all: fused input prep. grid (1024, 3).
//  y==0: cast k_c fp32 (T,512) -> bf16 Ab
//  y==1: BkT[n][k] = bf16(w_kv_b[k][(n>>7)*256 + (n&127)])   (32x32 transpose)
//  y==2: BvT[(h*128+v)][k] = bf16(w_uv[h][k][v])             (32x32 transpose)
// ---------------------------------------------------------------------------
__global__ __launch_bounds__(256) void stage_all(
    const float* __restrict__ k_c, const float* __restrict__ w_kv_b,
    const float* __restrict__ w_uv, unsigned short* __restrict__ Ab,
    unsigned short* __restrict__ BkT, unsigned short* __restrict__ BvT)
{
  __shared__ float tile[32][33];
  const int bx = blockIdx.x, role = blockIdx.y;
  const int tid = threadIdx.x;
  if (role == 0) {
    int i = (bx * 256 + tid) * 4;
    float4 v = *(const float4*)(k_c + i);
    ushort4 o = {f2bf(v.x), f2bf(v.y), f2bf(v.z), f2bf(v.w)};
    *(ushort4*)(Ab + i) = o;
    return;
  }
  const int tk = tid >> 3, tc4 = (tid & 7) * 4;
  const int wr = tid >> 3, wk4 = (tid & 7) * 4;
  if (role == 1) {
    const int k0 = (bx & 15) * 32, n0 = (bx >> 4) * 32;
    int n = n0 + tc4;
    int col = n + ((n >> 7) << 7);   // skip VDIM half of each head's 256 cols
    float4 v = *(const float4*)&w_kv_b[(size_t)(k0 + tk) * 4096 + col];
    tile[tk][tc4 + 0] = v.x; tile[tk][tc4 + 1] = v.y;
    tile[tk][tc4 + 2] = v.z; tile[tk][tc4 + 3] = v.w;
    __syncthreads();
    ushort4 o = {f2bf(tile[wk4 + 0][wr]), f2bf(tile[wk4 + 1][wr]),
                 f2bf(tile[wk4 + 2][wr]), f2bf(tile[wk4 + 3][wr])};
    *(ushort4*)&BkT[(size_t)(n0 + wr) * LORA_D + k0 + wk4] = o;
  } else {
    const int k0 = (bx & 15) * 32, v0 = ((bx >> 4) & 3) * 32, h = bx >> 6;
    float4 v = *(const float4*)&w_uv[(size_t)h * 65536 + (size_t)(k0 + tk) * 128 + v0 + tc4];
    tile[tk][tc4 + 0] = v.x; tile[tk][tc4 + 1] = v.y;
    tile[tk][tc4 + 2] = v.z; tile[tk][tc4 + 3] = v.w;
    __syncthreads();
    ushort4 o = {f2bf(tile[wk4 + 0][wr]), f2bf(tile[wk4 + 1][wr]),
                 f2bf(tile[wk4 + 2][wr]), f2bf(tile[wk4 + 3][wr])};
    *(ushort4*)&BvT[(size_t)(h * VDIM + v0 + wr) * LORA_D + k0 + wk4] = o;
  }
}

// ---------------------------------------------------------------------------
// prep_gemm: C(2048x2048) = Ab(2048x512) @ BT(2048x512)^T, bf16 in, fp32 acc.
// 128x128 tile, BK=32, double-buffered LDS + register prefetch, 1 barrier per
// chunk. grid (16, 32): by<16 -> K-epilogue (head by) + fused rope rows;
// by>=16 -> V^T epilogue.
// ---------------------------------------------------------------------------
__global__ __launch_bounds__(256) void prep_gemm(
    const unsigned short* __restrict__ A, const unsigned short* __restrict__ BkT,
    const unsigned short* __restrict__ BvT, const float* __restrict__ k_pe,
    unsigned short* __restrict__ Kb, unsigned short* __restrict__ Vt)
{
  __shared__ unsigned short As[2][128][40];
  __shared__ unsigned short Bs[2][128][40];
  const int m0 = blockIdx.x * 128;
  const int by = blockIdx.y;
  const int isK = (by < 16);
  const int n0 = (isK ? by : (by - 16)) * 128;
  const unsigned short* BT = isK ? BkT : BvT;
  const int tid = threadIdx.x;
  const int wid = tid >> 6, lane = tid & 63;
  const int l16 = lane & 15, quad = lane >> 4;
  const int wm = (wid >> 1) * 64, wn = (wid & 1) * 64;
  const int srow = tid >> 2, sc = tid & 3;
  uint4 areg[2], breg[2];

  auto load_regs = [&](int k0) {
#pragma unroll
    for (int i = 0; i < 2; ++i) {
      int row = srow + i * 64;
      areg[i] = *(const uint4*)(A + (size_t)(m0 + row) * LORA_D + k0 + sc * 8);
      breg[i] = *(const uint4*)(BT + (size_t)(n0 + row) * LORA_D + k0 + sc * 8);
    }
  };
  auto store_lds = [&](int b) {
#pragma unroll
    for (int i = 0; i < 2; ++i) {
      int row = srow + i * 64;
      *(uint4*)((char*)&As[b][row][0] + sc * 16) = areg[i];
      *(uint4*)((char*)&Bs[b][row][0] + sc * 16) = breg[i];
    }
  };

  f32x4 acc[4][4];
#pragma unroll
  for (int i = 0; i < 4; ++i)
#pragma unroll
    for (int j = 0; j < 4; ++j) acc[i][j] = (f32x4){0.f, 0.f, 0.f, 0.f};

  load_regs(0);
  store_lds(0);
  __syncthreads();
  for (int kc = 0; kc < 16; ++kc) {
    const int cur = kc & 1;
    if (kc < 15) load_regs((kc + 1) * 32);
    bf16x8 af[4], bfr[4];
#pragma unroll
    for (int t = 0; t < 4; ++t) {
      af[t] = *(const bf16x8*)&As[cur][wm + t * 16 + l16][quad * 8];
      bfr[t] = *(const bf16x8*)&Bs[cur][wn + t * 16 + l16][quad * 8];
    }
#pragma unroll
    for (int mt = 0; mt < 4; ++mt)
#pragma unroll
      for (int nt = 0; nt < 4; ++nt)
        acc[mt][nt] = __builtin_amdgcn_mfma_f32_16x16x32_bf16(af[mt], bfr[nt], acc[mt][nt], 0, 0, 0);
    if (kc < 15) store_lds(cur ^ 1);
    __syncthreads();
  }

  if (isK) {
    const int h = by;
#pragma unroll
    for (int mt = 0; mt < 4; ++mt)
#pragma unroll
      for (int nt = 0; nt < 4; ++nt) {
        int m = m0 + wm + mt * 16 + quad * 4;
        int d = wn + nt * 16 + l16;
#pragma unroll
        for (int r = 0; r < 4; ++r)
          Kb[(size_t)h * (T_SEQ * DQK) + (size_t)(m + r) * DQK + d] =
              f2bf(acc[mt][nt][r]);
      }
    // fused rope: Kb[h][m0+row][128+c] = bf16(k_pe[m0+row][c])
    for (int e = tid; e < 128 * 16; e += 256) {
      int row = e >> 4, c4 = (e & 15) * 4;
      float4 v = *(const float4*)&k_pe[(size_t)(m0 + row) * DROPE + c4];
      ushort4 o = {f2bf(v.x), f2bf(v.y), f2bf(v.z), f2bf(v.w)};
      *(ushort4*)&Kb[(size_t)h * (T_SEQ * DQK) + (size_t)(m0 + row) * DQK + DNOPE + c4] = o;
    }
  } else {
#pragma unroll
    for (int mt = 0; mt < 4; ++mt)
#pragma unroll
      for (int nt = 0; nt < 4; ++nt) {
        int n = n0 + wn + nt * 16 + l16;
        int m = m0 + wm + mt * 16 + quad * 4;
        ushort4 o = {f2bf(acc[mt][nt][0]), f2bf(acc[mt][nt][1]),
                     f2bf(acc[mt][nt][2]), f2bf(acc[mt][nt][3])};
        *(ushort4*)&Vt[(size_t)n * T_SEQ + m] = o;
      }
  }
}

// ---------------------------------------------------------------------------
// flash_mfma (wave-independent, transposed MFMA, zero LDS / zero barriers):
// one WAVE = (head, 16-row q-tile, <=16-chunk key segment); 5120 waves.
//   S^T = K @ Q^T  (A=K frags, B=Q frags; C col=l16 -> q, row=quad*4+r -> key)
//   O^T = V^T @ P^T (A=V^T frags, B=P^T built IN-REGISTER from S^T C-layout
//                    via 8 shfl + selects; no LDS round-trip)
// K frags ping-pong prefetched one chunk ahead (kfA/kfB); V issued at chunk
// top, consumed after QK+softmax. No-max softmax => split-K partials combine
// additively via atomics; norm_out divides.
// ---------------------------------------------------------------------------
__global__ __launch_bounds__(256, 2) void flash_mfma(
    const float* __restrict__ Q, const unsigned short* __restrict__ K,
    const unsigned short* __restrict__ Vt, float* __restrict__ outp,
    float* __restrict__ lacc)
{
  const int tid = threadIdx.x;
  const int wid = tid >> 6;
  const int lane = tid & 63;
  const int l16 = lane & 15;
  const int quad = lane >> 4;

  // ---- decode wave -> (head, q-tile j, chunk range) ----
  const int w = blockIdx.x * 4 + wid;           // 0..5119
  const int hh = w & 15;
  const int h = ((hh & 7) << 1) | (hh >> 3);    // spread heads across XCDs
  const int u = w >> 4;                          // 0..319 per head
  int j, cbeg, cend;
  if (u < 32)       { j = 32 + u;                 cbeg = 0;             cend = 16; }
  else if (u < 96)  { int q = u - 32; j = 64 + (q >> 1); cbeg = (q & 1) * 16; cend = cbeg + 16; }
  else if (u < 192) { int q = u - 96; j = 96 + q / 3;    cbeg = (q % 3) * 16; cend = cbeg + 16; }
  else              { j = 319 - u;    cbeg = (j >> 5) * 16; cend = (j + 2) >> 1; }
  const int qt0 = j * 16;
  const int qrow = qt0 + l16;

  const unsigned short* Kh  = K  + (size_t)h * T_SEQ * DQK;
  const unsigned short* Vth = Vt + (size_t)h * VDIM * T_SEQ;

  // ---- Q fragments (B-operand: n=l16 -> q-row, k=quad*8+j -> dim) ----
  bf16x8 qf[6];
  {
    const float* qp = Q + (size_t)qrow * (NHEAD * DQK) + h * DQK;
#pragma unroll
    for (int ks = 0; ks < 6; ++ks) {
      float4 a = *(const float4*)(qp + ks * 32 + quad * 8);
      float4 b = *(const float4*)(qp + ks * 32 + quad * 8 + 4);
      union { bf16x8 v; unsigned int u[4]; } t;
      t.u[0] = pkbf(a.x, a.y); t.u[1] = pkbf(a.z, a.w);
      t.u[2] = pkbf(b.x, b.y); t.u[3] = pkbf(b.z, b.w);
      qf[ks] = t.v;
    }
  }

  f32x4 oacc[8];
#pragma unroll
  for (int i = 0; i < 8; ++i) oacc[i] = (f32x4){0.f, 0.f, 0.f, 0.f};
  float lsum = 0.f;

  // A-operand K frags: m=l16 -> key (s0+16t+l16), k=quad*8+j -> dim
  auto loadK = [&](bf16x8* kf, int kb) {
    const int s0 = kb * KC;
#pragma unroll
    for (int t = 0; t < 2; ++t)
#pragma unroll
      for (int ks = 0; ks < 6; ++ks)
        kf[t * 6 + ks] =
            *(const bf16x8*)(Kh + (size_t)(s0 + t * 16 + l16) * DQK + ks * 32 + quad * 8);
  };

  const int L0 = ((quad & 1) << 5) + l16;   // source lane for j=0..3
  const int L1 = L0 + 16;                   // source lane for j=4..7

  auto compute = [&](bf16x8* kf, int kb) {
    const int s0 = kb * KC;
    // V^T A-frags: m=l16 -> vdim (mt*16+l16), k=quad*8+j -> key
    bf16x8 vf[8];
#pragma unroll
    for (int mt = 0; mt < 8; ++mt)
      vf[mt] = *(const bf16x8*)(Vth + (size_t)(mt * 16 + l16) * T_SEQ + s0 + quad * 8);
    // S^T = K @ Q^T (two 16-key tiles)
    f32x4 sacc[2];
    sacc[0] = (f32x4){0.f, 0.f, 0.f, 0.f};
    sacc[1] = (f32x4){0.f, 0.f, 0.f, 0.f};
#pragma unroll
    for (int ks = 0; ks < 6; ++ks) {
      sacc[0] = __builtin_amdgcn_mfma_f32_16x16x32_bf16(kf[ks],     qf[ks], sacc[0], 0, 0, 0);
      sacc[1] = __builtin_amdgcn_mfma_f32_16x16x32_bf16(kf[6 + ks], qf[ks], sacc[1], 0, 0, 0);
    }
    // exp + causal mask: lane holds s(q=qrow, key=s0+16t+4*quad+r)
    float ps[2][4];
#pragma unroll
    for (int t = 0; t < 2; ++t)
#pragma unroll
      for (int r = 0; r < 4; ++r) {
        int kidx = s0 + t * 16 + quad * 4 + r;
        float p = (kidx <= qrow) ? __expf(sacc[t][r] * SCALE_F) : 0.f;
        lsum += p;
        ps[t][r] = p;
      }
    // pack to bf16 pairs: P32[t][0]={r0,r1}, P32[t][1]={r2,r3}
    unsigned int P32t00 = pkbf(ps[0][0], ps[0][1]);
    unsigned int P32t01 = pkbf(ps[0][2], ps[0][3]);
    unsigned int P32t10 = pkbf(ps[1][0], ps[1][1]);
    unsigned int P32t11 = pkbf(ps[1][2], ps[1][3]);
    // build P^T B-frag in-register: target (l16, quad) j-th element = key
    // 8*quad+j = source lane (2(quad&1)+(j>>2))*16+l16, tile quad>>1, r=j&3
    unsigned int a0 = __shfl((int)P32t00, L0), b0 = __shfl((int)P32t10, L0);
    unsigned int a1 = __shfl((int)P32t01, L0), b1 = __shfl((int)P32t11, L0);
    unsigned int a2 = __shfl((int)P32t00, L1), b2 = __shfl((int)P32t10, L1);
    unsigned int a3 = __shfl((int)P32t01, L1), b3 = __shfl((int)P32t11, L1);
    union { bf16x8 v; unsigned int u[4]; } pb;
    pb.u[0] = (quad < 2) ? a0 : b0;
    pb.u[1] = (quad < 2) ? a1 : b1;
    pb.u[2] = (quad < 2) ? a2 : b2;
    pb.u[3] = (quad < 2) ? a3 : b3;
    // O^T += V^T @ P^T
#pragma unroll
    for (int mt = 0; mt < 8; ++mt)
      oacc[mt] = __builtin_amdgcn_mfma_f32_16x16x32_bf16(vf[mt], pb.v, oacc[mt], 0, 0, 0);
  };

  bf16x8 kfA[12], kfB[12];
  loadK(kfA, cbeg);
  int kb = cbeg;
  while (true) {
    if (kb + 1 < cend) loadK(kfB, kb + 1);
    compute(kfA, kb);
    ++kb; if (kb >= cend) break;
    if (kb + 1 < cend) loadK(kfA, kb + 1);
    compute(kfB, kb);
    ++kb; if (kb >= cend) break;
  }

  // ---- combine: l over quads, then atomics (unnormalized O^T) ----
  lsum += __shfl_xor(lsum, 16);
  lsum += __shfl_xor(lsum, 32);
  if (quad == 0) atomicAdd(&lacc[qrow * NHEAD + h], lsum);
#pragma unroll
  for (int mt = 0; mt < 8; ++mt)
#pragma unroll
    for (int r = 0; r < 4; ++r)
      atomicAdd(&outp[(size_t)qrow * (NHEAD * VDIM) + h * VDIM + mt * 16 + quad * 4 + r],
                oacc[mt][r]);
}

// ---------------------------------------------------------------------------
// norm_out: out[t][h*128+v] /= l[t][h]
// ---------------------------------------------------------------------------
__global__ __launch_bounds__(256) void norm_out(
    float* __restrict__ outp, const float* __restrict__ lacc)
{
  int e = (blockIdx.x * 256 + threadIdx.x) * 4;
  int t = e >> 11;
  int hh = (e >> 7) & 15;
  float inv = 1.f / lacc[t * NHEAD + hh];
  float4 v = *(float4*)(outp + e);
  v.x *= inv; v.y *= inv; v.z *= inv; v.w *= inv;
  *(float4*)(outp + e) = v;
}

// ---------------------------------------------------------------------------
extern "C" void kernel_launch(void* const* d_in, const int* in_sizes, int n_in,
                              void* d_out, int out_size, void* d_ws, size_t ws_size,
                              hipStream_t stream) {
  const float* query  = (const float*)d_in[0];  // (T, H, 192)
  const float* k_c    = (const float*)d_in[1];  // (T, 512)
  const float* k_pe   = (const float*)d_in[2];  // (T, 64)
  const float* w_kv_b = (const float*)d_in[3];  // (512, 4096)
  const float* w_uv   = (const float*)d_in[4];  // (16, 512, 128)
  float* outp = (float*)d_out;                  // (T, 2048)

  unsigned short* Kb  = (unsigned short*)d_ws;             // (H,T,192) bf16
  unsigned short* Vt  = Kb + (size_t)NHEAD * T_SEQ * DQK;  // (H,128,T) bf16
  unsigned short* Ab  = Vt + (size_t)NHEAD * VDIM * T_SEQ; // (T,512)
  unsigned short* BkT = Ab + (size_t)T_SEQ * LORA_D;       // (2048,512)
  unsigned short* BvT = BkT + (size_t)2048 * LORA_D;       // (2048,512)
  float* lacc = (float*)(BvT + (size_t)2048 * LORA_D);     // (T,16) fp32

  hipMemsetAsync(outp, 0, (size_t)T_SEQ * NHEAD * VDIM * sizeof(float), stream);
  hipMemsetAsync(lacc, 0, (size_t)T_SEQ * NHEAD * sizeof(float), stream);

  stage_all<<<dim3(1024, 3), 256, 0, stream>>>(k_c, w_kv_b, w_uv, Ab, BkT, BvT);
  prep_gemm<<<dim3(16, 32), 256, 0, stream>>>(Ab, BkT, BvT, k_pe, Kb, Vt);
  flash_mfma<<<1280, 256, 0, stream>>>(query, Kb, Vt, outp, lacc);
  norm_out<<<T_SEQ * NHEAD * VDIM / 1024, 256, 0, stream>>>(outp, lacc);
}